// Round 1
// baseline (242.073 us; speedup 1.0000x reference)
//
#include <hip/hip_runtime.h>

typedef __bf16 bf16x8 __attribute__((ext_vector_type(8)));
typedef float floatx4 __attribute__((ext_vector_type(4)));
typedef float floatx16 __attribute__((ext_vector_type(16)));

#define BB 4
#define CC 256
#define NN 4096

__device__ __forceinline__ unsigned short f2bf(float f) {
  union { float f; unsigned u; } v; v.f = f;
  unsigned r = v.u + 0x7fffu + ((v.u >> 16) & 1u);
  return (unsigned short)(r >> 16);
}

// ---------------- GroupNorm stats: 128 blocks, each reduces a contiguous 32768-float group ----
__global__ __launch_bounds__(256) void gn_stats(const float* __restrict__ x, float* __restrict__ mr) {
  int bg = blockIdx.x;
  const float* p = x + (size_t)bg * 32768;
  int t = threadIdx.x;
  float s = 0.f, q = 0.f;
#pragma unroll
  for (int it = 0; it < 32; ++it) {
    float4 v = *(const float4*)(p + it * 1024 + t * 4);
    s += v.x + v.y + v.z + v.w;
    q += v.x * v.x + v.y * v.y + v.z * v.z + v.w * v.w;
  }
#pragma unroll
  for (int off = 1; off < 64; off <<= 1) {
    s += __shfl_xor(s, off, 64);
    q += __shfl_xor(q, off, 64);
  }
  __shared__ float red[8];
  int w = t >> 6;
  if ((t & 63) == 0) { red[w] = s; red[4 + w] = q; }
  __syncthreads();
  if (t == 0) {
    float S = red[0] + red[1] + red[2] + red[3];
    float Q = red[4] + red[5] + red[6] + red[7];
    float mean = S * (1.f / 32768.f);
    float var = Q * (1.f / 32768.f) - mean * mean;
    mr[bg] = mean;
    mr[128 + bg] = rsqrtf(var + 1e-5f);
  }
}

// ---------------- normalize + transpose to normed[b][n][c] bf16 ----------------
__global__ __launch_bounds__(256) void gn_apply(const float* __restrict__ x, const float* __restrict__ mr,
                                                const float* __restrict__ gamma, const float* __restrict__ beta,
                                                unsigned short* __restrict__ normed) {
  int bid = blockIdx.x;              // b * 4(ctile) * 64(ntile)
  int nt = bid & 63;
  int ct = (bid >> 6) & 3;
  int b = bid >> 8;
  int c0 = ct * 64, n0 = nt * 64;
  __shared__ unsigned short T[64][80];   // [n][c], padded
  int t = threadIdx.x;
#pragma unroll
  for (int it = 0; it < 4; ++it) {
    int idx = it * 256 + t;
    int cl = idx >> 4;
    int n4 = (idx & 15) * 4;
    int c = c0 + cl;
    int bg = b * 32 + (c >> 3);
    float mean = mr[bg], rstd = mr[128 + bg];
    float sc = rstd * gamma[c];
    float sh = beta[c] - mean * sc;
    float4 v = *(const float4*)(x + ((size_t)(b * CC + c)) * NN + n0 + n4);
    T[n4 + 0][cl] = f2bf(v.x * sc + sh);
    T[n4 + 1][cl] = f2bf(v.y * sc + sh);
    T[n4 + 2][cl] = f2bf(v.z * sc + sh);
    T[n4 + 3][cl] = f2bf(v.w * sc + sh);
  }
  __syncthreads();
#pragma unroll
  for (int it = 0; it < 2; ++it) {
    int idx = it * 256 + t;
    int nl = idx >> 3, ck = idx & 7;
    uint4 val;
    unsigned short* pv = (unsigned short*)&val;
#pragma unroll
    for (int j = 0; j < 8; ++j) pv[j] = T[nl][ck * 8 + j];
    *(uint4*)(normed + ((size_t)b * NN + n0 + nl) * CC + c0 + ck * 8) = val;
  }
}

// ---------------- weight fp32 -> bf16 (q rows pre-scaled by log2(e)/sqrt(C)) ----------------
__global__ __launch_bounds__(256) void wconv(const float* __restrict__ wqkv, const float* __restrict__ wproj,
                                             unsigned short* __restrict__ wq_bf, unsigned short* __restrict__ wp_bf) {
  int i = blockIdx.x * 256 + threadIdx.x;      // 1024 blocks -> 262144
  if (i < 196608) {
    float v = wqkv[i];
    if (i < 65536) v *= 0.090168440055560213f;  // log2(e)/16
    wq_bf[i] = f2bf(v);
  } else {
    int j = i - 196608;
    wp_bf[j] = f2bf(wproj[j]);
  }
}

// ---------------- B^T GEMM: C[M][Nc] = A[M][256] * B[Nc][256]^T  (128x128 tiles) ----------------
template <int RESID>
__global__ __launch_bounds__(256) void gemm_bt(const unsigned short* __restrict__ A,
                                               const unsigned short* __restrict__ Bm,
                                               void* __restrict__ Cout, const float* __restrict__ resid,
                                               int mtiles, int ldc,
                                               long sA, long sB, long sC, long sR) {
  int mt = blockIdx.x % mtiles;
  int nt = blockIdx.x / mtiles;
  int b = blockIdx.y;
  int m0 = mt * 128, n0 = nt * 128;
  __shared__ unsigned short As[128][72];
  __shared__ unsigned short Bs[128][72];
  int t = threadIdx.x;
  int w = t >> 6, lane = t & 63;
  int l16 = lane & 15, quad = lane >> 4;
  int wr = w >> 1, wc = w & 1;
  const unsigned short* Ab = A + (size_t)b * sA + (size_t)m0 * 256;
  const unsigned short* Bb = Bm + (size_t)b * sB + (size_t)n0 * 256;
  floatx4 acc[4][4];
#pragma unroll
  for (int m = 0; m < 4; ++m)
#pragma unroll
    for (int n = 0; n < 4; ++n)
#pragma unroll
      for (int r = 0; r < 4; ++r) acc[m][n][r] = 0.f;

  for (int kb = 0; kb < 4; ++kb) {
    __syncthreads();
#pragma unroll
    for (int i = 0; i < 4; ++i) {
      int idx = i * 256 + t;
      int r = idx >> 3, ck = idx & 7;
      *(uint4*)&As[r][ck * 8] = *(const uint4*)(Ab + (size_t)r * 256 + kb * 64 + ck * 8);
      *(uint4*)&Bs[r][ck * 8] = *(const uint4*)(Bb + (size_t)r * 256 + kb * 64 + ck * 8);
    }
    __syncthreads();
#pragma unroll
    for (int kk = 0; kk < 2; ++kk) {
      bf16x8 af[4], bfr[4];
#pragma unroll
      for (int m = 0; m < 4; ++m) af[m] = *(const bf16x8*)&As[wr * 64 + m * 16 + l16][kk * 32 + quad * 8];
#pragma unroll
      for (int n = 0; n < 4; ++n) bfr[n] = *(const bf16x8*)&Bs[wc * 64 + n * 16 + l16][kk * 32 + quad * 8];
#pragma unroll
      for (int m = 0; m < 4; ++m)
#pragma unroll
        for (int n = 0; n < 4; ++n)
          acc[m][n] = __builtin_amdgcn_mfma_f32_16x16x32_bf16(af[m], bfr[n], acc[m][n], 0, 0, 0);
    }
  }
  size_t cb = (size_t)b * sC;
  size_t rb = (size_t)b * sR;
#pragma unroll
  for (int m = 0; m < 4; ++m)
#pragma unroll
    for (int n = 0; n < 4; ++n)
#pragma unroll
      for (int r = 0; r < 4; ++r) {
        int row = m0 + wr * 64 + m * 16 + quad * 4 + r;
        int col = n0 + wc * 64 + n * 16 + l16;
        size_t idx = (size_t)row * ldc + col;
        if (RESID)
          ((float*)Cout)[cb + idx] = acc[m][n][r] + resid[rb + idx];
        else
          ((unsigned short*)Cout)[cb + idx] = f2bf(acc[m][n][r]);
      }
}

// ---------------- fused attention: Br=64, Bc=64, 32x32x16 MFMA, no-max softmax (exp2 domain) ----
__global__ __launch_bounds__(256) void attn(const unsigned short* __restrict__ qk,   // [B][N][512] (q|k)
                                            const unsigned short* __restrict__ vbuf, // [B][C][N]
                                            unsigned short* __restrict__ obuf) {     // [B][N][C]
  // XCD-aware swizzle: XCD x handles batch x/2 so per-XCD L2 holds one batch's K/V
  int xcd = blockIdx.x & 7, slot = blockIdx.x >> 3;
  int b = xcd >> 1;
  int qt = slot * 2 + (xcd & 1);
  int i0 = qt * 64;

  __shared__ unsigned short Ks[64][264];   // K-tile [j][c] (also Q staging)
  __shared__ unsigned short VT[256][72];   // V-tile [c][j]
  __shared__ unsigned short Pb[2][32][72]; // P per row-group [i][j]
  __shared__ float Lb[2][2][32];

  int t = threadIdx.x, w = t >> 6, lane = t & 63;
  int l31 = lane & 31, hi = lane >> 5;
  int wr = w >> 1, wc = w & 1;

  // stage Q tile into Ks, pull into registers
  const unsigned short* qbase = qk + ((size_t)b * NN + i0) * 512;
#pragma unroll
  for (int i = 0; i < 8; ++i) {
    int idx = i * 256 + t;
    int r = idx >> 5, ck = idx & 31;
    *(uint4*)&Ks[r][ck * 8] = *(const uint4*)(qbase + (size_t)r * 512 + ck * 8);
  }
  __syncthreads();
  bf16x8 qreg[16];
#pragma unroll
  for (int ks = 0; ks < 16; ++ks)
    qreg[ks] = *(const bf16x8*)&Ks[wr * 32 + l31][ks * 16 + hi * 8];

  floatx16 oacc[4];
#pragma unroll
  for (int cf = 0; cf < 4; ++cf)
#pragma unroll
    for (int r = 0; r < 16; ++r) oacc[cf][r] = 0.f;
  float lacc[16];
#pragma unroll
  for (int r = 0; r < 16; ++r) lacc[r] = 0.f;

  for (int kt = 0; kt < 64; ++kt) {
    int j0 = kt * 64;
    __syncthreads();   // protects Ks/VT (and Pb) against still-pending reads
    const unsigned short* kb_ = qk + ((size_t)b * NN + j0) * 512 + 256;
#pragma unroll
    for (int i = 0; i < 8; ++i) {
      int idx = i * 256 + t;
      int r = idx >> 5, ck = idx & 31;
      *(uint4*)&Ks[r][ck * 8] = *(const uint4*)(kb_ + (size_t)r * 512 + ck * 8);
    }
    const unsigned short* vb_ = vbuf + (size_t)b * CC * NN + j0;
#pragma unroll
    for (int i = 0; i < 8; ++i) {
      int idx = i * 256 + t;
      int r = idx >> 3, ck = idx & 7;
      *(uint4*)&VT[r][ck * 8] = *(const uint4*)(vb_ + (size_t)r * NN + ck * 8);
    }
    __syncthreads();

    // S = Q K^T (wave tile 32x32), scores already in log2 domain (scale folded into w_q)
    floatx16 s;
#pragma unroll
    for (int r = 0; r < 16; ++r) s[r] = 0.f;
#pragma unroll
    for (int ks = 0; ks < 16; ++ks) {
      bf16x8 bk = *(const bf16x8*)&Ks[wc * 32 + l31][ks * 16 + hi * 8];
      s = __builtin_amdgcn_mfma_f32_32x32x16_bf16(qreg[ks], bk, s, 0, 0, 0);
    }
    // P = exp2(S); per-lane column-slice l accumulation (no cross-lane work per iter)
#pragma unroll
    for (int r = 0; r < 16; ++r) {
      float p = __builtin_amdgcn_exp2f(s[r]);
      lacc[r] += p;
      int row = (r & 3) + 8 * (r >> 2) + 4 * hi;
      Pb[wr][row][wc * 32 + l31] = f2bf(p);
    }
    __syncthreads();   // P visible to both col-waves

    // O += P V : wave computes rows wr*32.., cols wc*128..wc*128+128
#pragma unroll
    for (int ks = 0; ks < 4; ++ks) {
      bf16x8 ap = *(const bf16x8*)&Pb[wr][l31][ks * 16 + hi * 8];
#pragma unroll
      for (int cf = 0; cf < 4; ++cf) {
        bf16x8 bv = *(const bf16x8*)&VT[wc * 128 + cf * 32 + l31][ks * 16 + hi * 8];
        oacc[cf] = __builtin_amdgcn_mfma_f32_32x32x16_bf16(ap, bv, oacc[cf], 0, 0, 0);
      }
    }
  }

  // final l: reduce across 32 columns, then combine the two col-wave halves via LDS
#pragma unroll
  for (int r = 0; r < 16; ++r) {
    float v = lacc[r];
    v += __shfl_xor(v, 1, 64);
    v += __shfl_xor(v, 2, 64);
    v += __shfl_xor(v, 4, 64);
    v += __shfl_xor(v, 8, 64);
    v += __shfl_xor(v, 16, 64);
    lacc[r] = v;
  }
  __syncthreads();
  if (l31 == 0) {
#pragma unroll
    for (int r = 0; r < 16; ++r)
      Lb[wr][wc][(r & 3) + 8 * (r >> 2) + 4 * hi] = lacc[r];
  }
  __syncthreads();
#pragma unroll
  for (int r = 0; r < 16; ++r) {
    int row = (r & 3) + 8 * (r >> 2) + 4 * hi;
    float linv = 1.f / (Lb[wr][0][row] + Lb[wr][1][row]);
    int gi = i0 + wr * 32 + row;
#pragma unroll
    for (int cf = 0; cf < 4; ++cf) {
      int c = wc * 128 + cf * 32 + l31;
      obuf[((size_t)b * NN + gi) * CC + c] = f2bf(oacc[cf][r] * linv);
    }
  }
}

extern "C" void kernel_launch(void* const* d_in, const int* in_sizes, int n_in,
                              void* d_out, int out_size, void* d_ws, size_t ws_size,
                              hipStream_t stream) {
  const float* x     = (const float*)d_in[0];
  // d_in[1] = t (unused)
  const float* gamma = (const float*)d_in[2];
  const float* beta  = (const float*)d_in[3];
  const float* wqkv  = (const float*)d_in[4];
  const float* wproj = (const float*)d_in[5];
  float* out = (float*)d_out;

  char* p = (char*)d_ws;
  float* mr               = (float*)(p + 0);          //  1 KB  mean[128] | rstd[128]
  unsigned short* wq_bf   = (unsigned short*)(p + 1024);       // 384 KB
  unsigned short* wp_bf   = (unsigned short*)(p + 394240);     // 128 KB
  unsigned short* normed  = (unsigned short*)(p + 525312);     // 8 MB  [b][n][c]
  unsigned short* qkbuf   = (unsigned short*)(p + 8913920);    // 16 MB [b][n][512]
  unsigned short* vbuf    = (unsigned short*)(p + 25691136);   // 8 MB  [b][c][n]
  unsigned short* obuf    = (unsigned short*)(p + 34079744);   // 8 MB  [b][n][c]
  unsigned short* wv_bf   = wq_bf + 512 * 256;

  wconv<<<1024, 256, 0, stream>>>(wqkv, wproj, wq_bf, wp_bf);
  gn_stats<<<128, 256, 0, stream>>>(x, mr);
  gn_apply<<<1024, 256, 0, stream>>>(x, mr, gamma, beta, normed);
  // qk[b][n][o] = normed[b][n][:] . wqkv[o][:]  (o<512)
  gemm_bt<0><<<dim3(128, 4), 256, 0, stream>>>(normed, wq_bf, qkbuf, nullptr,
                                               32, 512, (long)NN * CC, 0L, (long)NN * 512, 0L);
  // v[b][c][n] = wv[c][:] . normed[b][n][:]
  gemm_bt<0><<<dim3(64, 4), 256, 0, stream>>>(wv_bf, normed, vbuf, nullptr,
                                              2, 4096, 0L, (long)NN * CC, (long)CC * NN, 0L);
  attn<<<256, 256, 0, stream>>>(qkbuf, vbuf, obuf);
  // out[b][co][n] = wproj[co][:] . obuf[b][n][:] + x[b][co][n]
  gemm_bt<1><<<dim3(64, 4), 256, 0, stream>>>(wp_bf, obuf, out, x,
                                              2, 4096, 0L, (long)NN * CC, (long)CC * NN, (long)CC * NN);
}